// Round 5
// baseline (241.454 us; speedup 1.0000x reference)
//
#include <hip/hip_runtime.h>
#include <math.h>

#define EMB_D 64
#define EMB_K 1024
#define NROWS 65536            // 64*32*32
#define QELEMS (NROWS * EMB_D) // 4194304

// d_out layout (floats): [0, 4194304) quantized | [4194304] loss | [4194305, ...) indices (as float)
// d_ws layout (bytes):   [0, 262144) Et float[1024][64] | [262144, 266240) esq float[1024]
//                        [266240, 266248) double loss accumulator

// ---------------- Kernel A: transpose codebook, per-code ||e||^2, zero loss accum ----------------
__global__ __launch_bounds__(256) void prep_kernel(const float* __restrict__ E,
                                                   float* __restrict__ Et,
                                                   float* __restrict__ esq,
                                                   double* lsum) {
    int k = blockIdx.x * 256 + threadIdx.x;
    if (k == 0) *lsum = 0.0;  // ws is re-poisoned 0xAA before every launch
    if (k >= EMB_K) return;
    float s = 0.f;
#pragma unroll
    for (int d = 0; d < EMB_D; ++d) {
        float v = E[d * EMB_K + k];       // coalesced read across k
        Et[k * EMB_D + d] = v;            // contiguous per-thread write
        s = fmaf(v, v, s);                // same chain order as round-1 (d ascending)
    }
    esq[k] = s;
}

// accumulate 4 products into acc, in x/y/z/w order (matches round-1's i-ascending chain)
#define DOT4(acc, q, e)                                    \
    do {                                                   \
        acc = fmaf((q).x, (e).x, acc);                     \
        acc = fmaf((q).y, (e).y, acc);                     \
        acc = fmaf((q).z, (e).z, acc);                     \
        acc = fmaf((q).w, (e).w, acc);                     \
    } while (0)

// Pin the 4 components of a float4 into VGPRs as asm-defined values:
// blocks rematerialization-by-reload (the round-3 failure mode).
#define PIN4(v) asm volatile("" : "+v"((v).x), "+v"((v).y), "+v"((v).z), "+v"((v).w))

// ---------------- Kernel B: fused argmin + quantize + loss ----------------
// Block = 4 waves over the SAME 64 rows; wave w scans codes [w*256, w*256+256).
// k0 via readfirstlane -> provably wave-uniform -> codebook/esq reads are
// SCALAR loads (SMEM pipe); inner loop is v_fmac v,s,v.
// __launch_bounds__(256, 2): 256-reg unified budget. Round 4 showed that a
// 128-reg budget makes RA store the 64-float x row in AGPRs (v_accvgpr_read
// per use = 2 issue slots per FMA). With the cap relaxed, x stays in VGPRs.
__global__ __launch_bounds__(256, 2) void main_kernel(const float* X,
                                                      const float* __restrict__ Et,
                                                      const float* __restrict__ esq,
                                                      float* __restrict__ quant,
                                                      float* __restrict__ idxf,
                                                      double* lsum) {
    __shared__ float sd[4][64];
    __shared__ int   si[4][64];
    __shared__ int   sidx[64];

    const int lane = threadIdx.x & 63;
    const int w    = threadIdx.x >> 6;
    const int rowbase = blockIdx.x * 64;

    // ---- load this lane's row into 16 explicit float4 registers ----
    const float4* xr = reinterpret_cast<const float4*>(X + (size_t)(rowbase + lane) * EMB_D);
    float4 x0 = xr[0],  x1 = xr[1],  x2 = xr[2],  x3 = xr[3];
    float4 x4 = xr[4],  x5 = xr[5],  x6 = xr[6],  x7 = xr[7];
    float4 x8 = xr[8],  x9 = xr[9],  x10 = xr[10], x11 = xr[11];
    float4 x12 = xr[12], x13 = xr[13], x14 = xr[14], x15 = xr[15];

    float xsq = 0.f;
    DOT4(xsq, x0, x0);   DOT4(xsq, x1, x1);   DOT4(xsq, x2, x2);   DOT4(xsq, x3, x3);
    DOT4(xsq, x4, x4);   DOT4(xsq, x5, x5);   DOT4(xsq, x6, x6);   DOT4(xsq, x7, x7);
    DOT4(xsq, x8, x8);   DOT4(xsq, x9, x9);   DOT4(xsq, x10, x10); DOT4(xsq, x11, x11);
    DOT4(xsq, x12, x12); DOT4(xsq, x13, x13); DOT4(xsq, x14, x14); DOT4(xsq, x15, x15);

    // Force the whole row to be register-resident, irreversibly.
    PIN4(x0);  PIN4(x1);  PIN4(x2);  PIN4(x3);
    PIN4(x4);  PIN4(x5);  PIN4(x6);  PIN4(x7);
    PIN4(x8);  PIN4(x9);  PIN4(x10); PIN4(x11);
    PIN4(x12); PIN4(x13); PIN4(x14); PIN4(x15);

    // wave-uniform code-chunk base (readfirstlane => known-uniform => s_load)
    const int k0 = __builtin_amdgcn_readfirstlane(w) * (EMB_K / 4);

    float bestd = INFINITY;
    int   besti = 0;
    for (int k = k0; k < k0 + EMB_K / 4; k += 2) {   // 2 codes in flight (2 FMA chains)
        const float4* e0 = reinterpret_cast<const float4*>(Et + (size_t)k * EMB_D);
        const float4* e1 = e0 + 16;
        float d0 = 0.f, d1 = 0.f;
#define STEP(i) { float4 a = e0[i]; float4 b = e1[i]; DOT4(d0, x##i, a); DOT4(d1, x##i, b); }
        STEP(0)  STEP(1)  STEP(2)  STEP(3)
        STEP(4)  STEP(5)  STEP(6)  STEP(7)
        STEP(8)  STEP(9)  STEP(10) STEP(11)
        STEP(12) STEP(13) STEP(14) STEP(15)
#undef STEP
        float dist0 = (xsq - 2.0f * d0) + esq[k];
        float dist1 = (xsq - 2.0f * d1) + esq[k + 1];
        if (dist0 < bestd) { bestd = dist0; besti = k; }
        if (dist1 < bestd) { bestd = dist1; besti = k + 1; }
    }
    sd[w][lane] = bestd;
    si[w][lane] = besti;
    __syncthreads();

    // ---- combine the 4 k-chunks (ascending w keeps lowest index on ties) ----
    if (threadIdx.x < 64) {
        float bd = sd[0][lane];
        int   bi = si[0][lane];
#pragma unroll
        for (int u = 1; u < 4; ++u) {
            if (sd[u][lane] < bd) { bd = sd[u][lane]; bi = si[u][lane]; }
        }
        sidx[lane] = bi;
        idxf[rowbase + lane] = (float)bi;
    }
    __syncthreads();

    // ---- fused quantize + loss: thread t handles row t>>2, quarter t&3 (coalesced) ----
    {
        const int r = threadIdx.x >> 2;
        const int p = threadIdx.x & 3;
        const int k = sidx[r];
        const float4* xq = reinterpret_cast<const float4*>(X + (size_t)(rowbase + r) * EMB_D) + p * 4;
        const float4* qq = reinterpret_cast<const float4*>(Et + (size_t)k * EMB_D) + p * 4;
        float4*       oq = reinterpret_cast<float4*>(quant + (size_t)(rowbase + r) * EMB_D) + p * 4;
        float ps = 0.f;
#pragma unroll
        for (int u = 0; u < 4; ++u) {
            float4 xx = xq[u];
            float4 q  = qq[u];
            float dx = q.x - xx.x, dy = q.y - xx.y, dz = q.z - xx.z, dw = q.w - xx.w;
            oq[u] = make_float4(xx.x + dx, xx.y + dy, xx.z + dz, xx.w + dw);
            ps += dx * dx + dy * dy + dz * dz + dw * dw;
        }
#pragma unroll
        for (int off = 32; off > 0; off >>= 1) ps += __shfl_down(ps, off, 64);
        if (lane == 0) atomicAdd(lsum, (double)ps);
    }
}

// ---------------- Kernel D: finalize loss ----------------
__global__ void finalize_kernel(const double* lsum, float* loss_out) {
    double m = *lsum / (double)QELEMS;
    *loss_out = (float)(m + 0.25 * m);  // e_latent + BETA * q_latent (same value)
}

extern "C" void kernel_launch(void* const* d_in, const int* in_sizes, int n_in,
                              void* d_out, int out_size, void* d_ws, size_t ws_size,
                              hipStream_t stream) {
    const float* X = (const float*)d_in[0];   // [64,32,32,64] = 4194304 floats
    const float* E = (const float*)d_in[1];   // [64,1024]     = 65536 floats

    float* out = (float*)d_out;
    float* quant = out;                  // [0, 4194304)
    float* loss  = out + QELEMS;         // [4194304]
    float* idxf  = out + QELEMS + 1;     // [4194305, ...)

    char* ws = (char*)d_ws;
    float*  Et   = (float*)(ws);             // 256 KiB
    float*  esq  = (float*)(ws + 262144);    // 4 KiB
    double* lsum = (double*)(ws + 266240);   // 8 B

    prep_kernel<<<4, 256, 0, stream>>>(E, Et, esq, lsum);
    main_kernel<<<NROWS / 64, 256, 0, stream>>>(X, Et, esq, quant, idxf, lsum);
    finalize_kernel<<<1, 1, 0, stream>>>(lsum, loss);
}

// Round 6
// 240.920 us; speedup vs baseline: 1.0022x; 1.0022x over previous
//
#include <hip/hip_runtime.h>
#include <math.h>

#define EMB_D 64
#define EMB_K 1024
#define NROWS 65536            // 64*32*32
#define QELEMS (NROWS * EMB_D) // 4194304

// d_out layout (floats): [0, 4194304) quantized | [4194304] loss | [4194305, ...) indices (as float)
// d_ws layout (bytes):   [0, 262144) Et float[1024][64] | [262144, 266240) esq float[1024]
//                        [266240, 266248) double loss accumulator

// ---------------- Kernel A: transpose codebook (LDS, coalesced both sides) ----------------
// Block b covers codes [b*256, b*256+256). Reads E[d][k] coalesced, stages in
// padded LDS (stride 65 -> conflict-free), writes Et rows coalesced.
// esq chain: fmaf over d ascending — identical order to all prior rounds.
__global__ __launch_bounds__(256) void prep_kernel(const float* __restrict__ E,
                                                   float* __restrict__ Et,
                                                   float* __restrict__ esq,
                                                   double* lsum) {
    __shared__ float tile[256][65];
    const int t = threadIdx.x;
    const int kbase = blockIdx.x * 256;
    if (blockIdx.x == 0 && t == 0) *lsum = 0.0;  // ws re-poisoned 0xAA each launch

    // read: lane-consecutive k -> coalesced; LDS write stride 65 -> conflict-free
#pragma unroll
    for (int d = 0; d < EMB_D; ++d) tile[t][d] = E[d * EMB_K + kbase + t];
    __syncthreads();

    // ||e||^2 for this thread's code (d-ascending fmaf chain, same as rounds 1-5)
    {
        float s = 0.f;
#pragma unroll
        for (int d = 0; d < EMB_D; ++d) { float v = tile[t][d]; s = fmaf(v, v, s); }
        esq[kbase + t] = s;
    }

    // write: flat element m = j*256+t of this block's 256x64 chunk -> coalesced
#pragma unroll
    for (int j = 0; j < EMB_D; ++j) {
        int m = j * 256 + t;
        Et[(size_t)kbase * EMB_D + m] = tile[m >> 6][m & 63];
    }
}

// accumulate 4 products into acc, in x/y/z/w order (d-ascending chain)
#define DOT4(acc, q, e)                                    \
    do {                                                   \
        acc = fmaf((q).x, (e).x, acc);                     \
        acc = fmaf((q).y, (e).y, acc);                     \
        acc = fmaf((q).z, (e).z, acc);                     \
        acc = fmaf((q).w, (e).w, acc);                     \
    } while (0)

// Pin float4 components as asm-defined values (blocks remat-by-reload).
#define PIN4(v) asm volatile("" : "+v"((v).x), "+v"((v).y), "+v"((v).z), "+v"((v).w))

// 8-FMA chain segment with FORCED allocation: e -> SGPR ("s"), x -> VGPR ("v").
// v_fmac_f32 is fused (single rounding) == fmaf. Chain order: d = B..B+7 ascending.
#define FMA8(acc, E, B, va, vb)                                              \
    asm("v_fmac_f32 %0, %1, %9\n\t"                                          \
        "v_fmac_f32 %0, %2, %10\n\t"                                         \
        "v_fmac_f32 %0, %3, %11\n\t"                                         \
        "v_fmac_f32 %0, %4, %12\n\t"                                         \
        "v_fmac_f32 %0, %5, %13\n\t"                                         \
        "v_fmac_f32 %0, %6, %14\n\t"                                         \
        "v_fmac_f32 %0, %7, %15\n\t"                                         \
        "v_fmac_f32 %0, %8, %16"                                             \
        : "+v"(acc)                                                          \
        : "s"((E)[(B) + 0]), "s"((E)[(B) + 1]), "s"((E)[(B) + 2]),           \
          "s"((E)[(B) + 3]), "s"((E)[(B) + 4]), "s"((E)[(B) + 5]),           \
          "s"((E)[(B) + 6]), "s"((E)[(B) + 7]),                              \
          "v"((va).x), "v"((va).y), "v"((va).z), "v"((va).w),                \
          "v"((vb).x), "v"((vb).y), "v"((vb).z), "v"((vb).w))

// ---------------- Kernel B: fused argmin + quantize + loss ----------------
// Block = 4 waves over the SAME 64 rows; wave w scans codes [w*256, w*256+256).
// k0 via readfirstlane -> provably wave-uniform -> e/esq reads are SCALAR loads.
// The FMA8 asm constraints force x into VGPRs and e into SGPRs at every use —
// the register allocator can no longer shelve the x row (rounds 3-5 failure).
__global__ __launch_bounds__(256, 2) void main_kernel(const float* X,
                                                      const float* __restrict__ Et,
                                                      const float* __restrict__ esq,
                                                      float* __restrict__ quant,
                                                      float* __restrict__ idxf,
                                                      double* lsum) {
    __shared__ float sd[4][64];
    __shared__ int   si[4][64];
    __shared__ int   sidx[64];

    const int lane = threadIdx.x & 63;
    const int w    = threadIdx.x >> 6;
    const int rowbase = blockIdx.x * 64;

    // ---- load this lane's row into 16 explicit float4 registers ----
    const float4* xr = reinterpret_cast<const float4*>(X + (size_t)(rowbase + lane) * EMB_D);
    float4 x0 = xr[0],  x1 = xr[1],  x2 = xr[2],  x3 = xr[3];
    float4 x4 = xr[4],  x5 = xr[5],  x6 = xr[6],  x7 = xr[7];
    float4 x8 = xr[8],  x9 = xr[9],  x10 = xr[10], x11 = xr[11];
    float4 x12 = xr[12], x13 = xr[13], x14 = xr[14], x15 = xr[15];

    float xsq = 0.f;
    DOT4(xsq, x0, x0);   DOT4(xsq, x1, x1);   DOT4(xsq, x2, x2);   DOT4(xsq, x3, x3);
    DOT4(xsq, x4, x4);   DOT4(xsq, x5, x5);   DOT4(xsq, x6, x6);   DOT4(xsq, x7, x7);
    DOT4(xsq, x8, x8);   DOT4(xsq, x9, x9);   DOT4(xsq, x10, x10); DOT4(xsq, x11, x11);
    DOT4(xsq, x12, x12); DOT4(xsq, x13, x13); DOT4(xsq, x14, x14); DOT4(xsq, x15, x15);

    PIN4(x0);  PIN4(x1);  PIN4(x2);  PIN4(x3);
    PIN4(x4);  PIN4(x5);  PIN4(x6);  PIN4(x7);
    PIN4(x8);  PIN4(x9);  PIN4(x10); PIN4(x11);
    PIN4(x12); PIN4(x13); PIN4(x14); PIN4(x15);
    __syncthreads();   // fence: x loads cannot sink into the k-loop

    // wave-uniform code-chunk base (readfirstlane => known-uniform => s_load)
    const int k0 = __builtin_amdgcn_readfirstlane(w) * (EMB_K / 4);

    float bestd = INFINITY;
    int   besti = 0;
    for (int k = k0; k < k0 + EMB_K / 4; ++k) {
        const float* e = Et + (size_t)k * EMB_D;   // uniform -> SGPR loads
        float acc = 0.f;
        FMA8(acc, e, 0,  x0,  x1);
        FMA8(acc, e, 8,  x2,  x3);
        FMA8(acc, e, 16, x4,  x5);
        FMA8(acc, e, 24, x6,  x7);
        FMA8(acc, e, 32, x8,  x9);
        FMA8(acc, e, 40, x10, x11);
        FMA8(acc, e, 48, x12, x13);
        FMA8(acc, e, 56, x14, x15);
        float dist = (xsq - 2.0f * acc) + esq[k];  // same association as rounds 1-5
        if (dist < bestd) { bestd = dist; besti = k; }  // strict '<': first-wins
    }
    sd[w][lane] = bestd;
    si[w][lane] = besti;
    __syncthreads();

    // ---- combine the 4 k-chunks (ascending w keeps lowest index on ties) ----
    if (threadIdx.x < 64) {
        float bd = sd[0][lane];
        int   bi = si[0][lane];
#pragma unroll
        for (int u = 1; u < 4; ++u) {
            if (sd[u][lane] < bd) { bd = sd[u][lane]; bi = si[u][lane]; }
        }
        sidx[lane] = bi;
        idxf[rowbase + lane] = (float)bi;
    }
    __syncthreads();

    // ---- fused quantize + loss: thread t handles row t>>2, quarter t&3 (coalesced) ----
    {
        const int r = threadIdx.x >> 2;
        const int p = threadIdx.x & 3;
        const int k = sidx[r];
        const float4* xq = reinterpret_cast<const float4*>(X + (size_t)(rowbase + r) * EMB_D) + p * 4;
        const float4* qq = reinterpret_cast<const float4*>(Et + (size_t)k * EMB_D) + p * 4;
        float4*       oq = reinterpret_cast<float4*>(quant + (size_t)(rowbase + r) * EMB_D) + p * 4;
        float ps = 0.f;
#pragma unroll
        for (int u = 0; u < 4; ++u) {
            float4 xx = xq[u];
            float4 q  = qq[u];
            float dx = q.x - xx.x, dy = q.y - xx.y, dz = q.z - xx.z, dw = q.w - xx.w;
            oq[u] = make_float4(xx.x + dx, xx.y + dy, xx.z + dz, xx.w + dw);
            ps += dx * dx + dy * dy + dz * dz + dw * dw;
        }
#pragma unroll
        for (int off = 32; off > 0; off >>= 1) ps += __shfl_down(ps, off, 64);
        if (lane == 0) atomicAdd(lsum, (double)ps);
    }
}

// ---------------- Kernel D: finalize loss ----------------
__global__ void finalize_kernel(const double* lsum, float* loss_out) {
    double m = *lsum / (double)QELEMS;
    *loss_out = (float)(m + 0.25 * m);  // e_latent + BETA * q_latent (same value)
}

extern "C" void kernel_launch(void* const* d_in, const int* in_sizes, int n_in,
                              void* d_out, int out_size, void* d_ws, size_t ws_size,
                              hipStream_t stream) {
    const float* X = (const float*)d_in[0];   // [64,32,32,64] = 4194304 floats
    const float* E = (const float*)d_in[1];   // [64,1024]     = 65536 floats

    float* out = (float*)d_out;
    float* quant = out;                  // [0, 4194304)
    float* loss  = out + QELEMS;         // [4194304]
    float* idxf  = out + QELEMS + 1;     // [4194305, ...)

    char* ws = (char*)d_ws;
    float*  Et   = (float*)(ws);             // 256 KiB
    float*  esq  = (float*)(ws + 262144);    // 4 KiB
    double* lsum = (double*)(ws + 266240);   // 8 B

    prep_kernel<<<EMB_K / 256, 256, 0, stream>>>(E, Et, esq, lsum);
    main_kernel<<<NROWS / 64, 256, 0, stream>>>(X, Et, esq, quant, idxf, lsum);
    finalize_kernel<<<1, 1, 0, stream>>>(lsum, loss);
}